// Round 1
// 861.727 us; speedup vs baseline: 1.2272x; 1.2272x over previous
//
#include <hip/hip_runtime.h>

typedef __attribute__((ext_vector_type(8))) short short8;
typedef __attribute__((ext_vector_type(4))) short bf16x4;
typedef __attribute__((ext_vector_type(4))) float f32x4;

__device__ __forceinline__ f32x4 mfma16(short8 a, short8 b, f32x4 c) {
  return __builtin_amdgcn_mfma_f32_16x16x32_bf16(a, b, c, 0, 0, 0);
}

__device__ __forceinline__ short f2bf(float f) {  // RNE float->bf16
  union { float f; unsigned u; } v; v.f = f;
  unsigned r = (v.u + 0x7fffu + ((v.u >> 16) & 1u)) >> 16;
  return (short)r;
}

// Async global->LDS, 16B per lane. LDS dest must be the wave-uniform base;
// HW writes base + lane*16 (linear). Source address is per-lane.
__device__ __forceinline__ void gload16(const short* g, short* l) {
  __builtin_amdgcn_global_load_lds(
      (const __attribute__((address_space(1))) void*)g,
      (__attribute__((address_space(3))) void*)l, 16, 0, 0);
}

// ---------------- fp32 -> bf16 streaming convert ----------------
__global__ __launch_bounds__(256) void cvt_k(const float* __restrict__ src,
                                             short* __restrict__ dst, long n8) {
  long i = (long)blockIdx.x * 256 + threadIdx.x;
  const long stride = (long)gridDim.x * 256;
  for (; i < n8; i += stride) {
    float4 a = *(const float4*)(src + i * 8);
    float4 b = *(const float4*)(src + i * 8 + 4);
    short8 o = {f2bf(a.x), f2bf(a.y), f2bf(a.z), f2bf(a.w),
                f2bf(b.x), f2bf(b.y), f2bf(b.z), f2bf(b.w)};
    *(short8*)(dst + i * 8) = o;
  }
}

// ---------------- QKV GEMM: O[r][j] = sum_k X[r][k] * W[j][k] ----------------
// X: bf16 [M][768], W: bf16 [2304][768], O: bf16 [M][2304]. z=0 -> x, z=1 -> x_hsi.
__global__ __launch_bounds__(256) void gemm_qkv_k(
    const short* __restrict__ A0, const short* __restrict__ A1,
    const short* __restrict__ W,
    short* __restrict__ O0, short* __restrict__ O1) {
  __shared__ __align__(16) short As[128 * 32];
  __shared__ __align__(16) short Bs[128 * 32];
  const int tid = threadIdx.x;
  const int lane = tid & 63, wv = tid >> 6;
  const int l15 = lane & 15, q4 = lane >> 4;
  const int m0 = blockIdx.x * 128, n0 = blockIdx.y * 128;
  const short* A = blockIdx.z ? A1 : A0;
  short* O = blockIdx.z ? O1 : O0;
  const int wm = wv & 1, wn = wv >> 1;

  // staging slot s = tid + i*256 -> row s>>2, col (s&3)*8 ; LDS offset s*8 (linear)
  const int s0 = tid, s1 = tid + 256;
  const long ga0 = (long)(m0 + (s0 >> 2)) * 768 + (s0 & 3) * 8;
  const long ga1 = (long)(m0 + (s1 >> 2)) * 768 + (s1 & 3) * 8;
  const long gb0 = (long)(n0 + (s0 >> 2)) * 768 + (s0 & 3) * 8;
  const long gb1 = (long)(n0 + (s1 >> 2)) * 768 + (s1 & 3) * 8;
  short* lA0 = &As[(wv * 64) * 8];
  short* lA1 = &As[(wv * 64 + 256) * 8];
  short* lB0 = &Bs[(wv * 64) * 8];
  short* lB1 = &Bs[(wv * 64 + 256) * 8];

  f32x4 acc[4][4] = {};
  for (int k0 = 0; k0 < 768; k0 += 32) {
    __syncthreads();  // previous iteration's LDS readers done
    gload16(A + ga0 + k0, lA0);
    gload16(A + ga1 + k0, lA1);
    gload16(W + gb0 + k0, lB0);
    gload16(W + gb1 + k0, lB1);
    __syncthreads();  // drains vmcnt(0): tile resident
    short8 af[4], bf[4];
#pragma unroll
    for (int i = 0; i < 4; ++i)
      af[i] = *(const short8*)&As[(wm * 64 + i * 16 + l15) * 32 + q4 * 8];
#pragma unroll
    for (int j = 0; j < 4; ++j)
      bf[j] = *(const short8*)&Bs[(wn * 64 + j * 16 + l15) * 32 + q4 * 8];
#pragma unroll
    for (int i = 0; i < 4; ++i)
#pragma unroll
      for (int j = 0; j < 4; ++j)
        acc[i][j] = mfma16(af[i], bf[j], acc[i][j]);
  }
#pragma unroll
  for (int i = 0; i < 4; ++i)
#pragma unroll
    for (int j = 0; j < 4; ++j) {
      const int col = n0 + wn * 64 + j * 16 + l15;
#pragma unroll
      for (int r = 0; r < 4; ++r) {
        const int row = m0 + wm * 64 + i * 16 + q4 * 4 + r;
        O[(long)row * 2304 + col] = f2bf(acc[i][j][r]);
      }
    }
}

// ---------------- Attention (ws bf16 in, ws bf16 out) ----------------
// One block = 64 queries of one (b,h,kind); wave = 16 queries.
// NK=128: mt (t=0..1). NK=384: t=0..3 -> s (qkvx), t=4..7 -> s_hsi (qkvh).
template <int NK>
__global__ __launch_bounds__(256) void attn_k(
    const short* __restrict__ qkvx, const short* __restrict__ qkvh,
    short* __restrict__ omt, short* __restrict__ os, short* __restrict__ osh) {
  constexpr int NT = NK / 16;
  constexpr int KT = NK / 64;
  constexpr int PSTR = NK + 8;
  constexpr int T = (NK == 128) ? 2 : 8;
  __shared__ __align__(16) short kv[64 * 72];     // K tile, then V^T tile
  __shared__ __align__(16) short sp[64 * PSTR];   // P (unnormalized), bf16

  const int tid = threadIdx.x, lane = tid & 63, wv = tid >> 6;
  const int l15 = lane & 15, q4 = lane >> 4;
  const int bx = blockIdx.x;
  const int b = bx / (12 * T);
  const int rr = bx % (12 * T);
  const int h = rr / T, t = rr % T;

  const short* src;
  short* outb;
  int q0;
  if (NK == 128) {
    src = qkvx;
    outb = omt + ((long)b * 128 + t * 64) * 768 + h * 64;
    q0 = t * 64;
  } else {
    const int tt = t & 3;
    const bool hs = t >= 4;
    src = hs ? qkvh : qkvx;
    outb = (hs ? osh : os) + ((long)b * 256 + tt * 64) * 768 + h * 64;
    q0 = 128 + tt * 64;
  }
  const short* qb = src + ((long)(b * 384 + q0 + wv * 16)) * 2304 + h * 64;
  const short* kb = src + (long)b * 384 * 2304 + 768 + h * 64;
  const short* vb = kb + 768;

  short8 qf0 = *(const short8*)(qb + (long)l15 * 2304 + q4 * 8);
  short8 qf1 = *(const short8*)(qb + (long)l15 * 2304 + 32 + q4 * 8);

  // ---- S = Q K^T ----
  f32x4 sacc[NT] = {};
#pragma unroll
  for (int kt = 0; kt < KT; ++kt) {
#pragma unroll
    for (int i = 0; i < 2; ++i) {
      const int c2 = tid + i * 256;
      const int key = c2 >> 3, dg = c2 & 7;
      short8 kvv = *(const short8*)(kb + (long)(kt * 64 + key) * 2304 + dg * 8);
      *(short8*)&kv[key * 72 + dg * 8] = kvv;
    }
    __syncthreads();
#pragma unroll
    for (int j = 0; j < 4; ++j) {
      short8 kf0 = *(const short8*)&kv[(j * 16 + l15) * 72 + q4 * 8];
      short8 kf1 = *(const short8*)&kv[(j * 16 + l15) * 72 + 32 + q4 * 8];
      sacc[kt * 4 + j] = mfma16(qf0, kf0, sacc[kt * 4 + j]);
      sacc[kt * 4 + j] = mfma16(qf1, kf1, sacc[kt * 4 + j]);
    }
    __syncthreads();
  }

  // ---- softmax ----
  const float scale = 0.125f;
  float mx[4] = {-3e38f, -3e38f, -3e38f, -3e38f};
#pragma unroll
  for (int nt = 0; nt < NT; ++nt)
#pragma unroll
    for (int r = 0; r < 4; ++r) mx[r] = fmaxf(mx[r], sacc[nt][r]);
#pragma unroll
  for (int r = 0; r < 4; ++r) {
    mx[r] = fmaxf(mx[r], __shfl_xor(mx[r], 1));
    mx[r] = fmaxf(mx[r], __shfl_xor(mx[r], 2));
    mx[r] = fmaxf(mx[r], __shfl_xor(mx[r], 4));
    mx[r] = fmaxf(mx[r], __shfl_xor(mx[r], 8));
  }
  float sm[4] = {0.f, 0.f, 0.f, 0.f};
#pragma unroll
  for (int nt = 0; nt < NT; ++nt)
#pragma unroll
    for (int r = 0; r < 4; ++r) {
      float e = __expf((sacc[nt][r] - mx[r]) * scale);
      sm[r] += e;
      sp[(wv * 16 + q4 * 4 + r) * PSTR + nt * 16 + l15] = f2bf(e);
    }
#pragma unroll
  for (int r = 0; r < 4; ++r) {
    sm[r] += __shfl_xor(sm[r], 1);
    sm[r] += __shfl_xor(sm[r], 2);
    sm[r] += __shfl_xor(sm[r], 4);
    sm[r] += __shfl_xor(sm[r], 8);
  }

  // ---- O = P V ----
  f32x4 oacc[4] = {};
#pragma unroll
  for (int kt = 0; kt < KT; ++kt) {
    __syncthreads();
#pragma unroll
    for (int i = 0; i < 2; ++i) {
      const int c2 = tid + i * 256;
      const int key = c2 >> 3, dg = c2 & 7;
      short8 vvv = *(const short8*)(vb + (long)(kt * 64 + key) * 2304 + dg * 8);
#pragma unroll
      for (int e = 0; e < 8; ++e) kv[(dg * 8 + e) * 72 + key] = vvv[e];
    }
    __syncthreads();
#pragma unroll
    for (int ks = 0; ks < 2; ++ks) {
      short8 pf = *(const short8*)&sp[(wv * 16 + l15) * PSTR + kt * 64 + ks * 32 + q4 * 8];
#pragma unroll
      for (int n2 = 0; n2 < 4; ++n2) {
        short8 vf = *(const short8*)&kv[(n2 * 16 + l15) * 72 + ks * 32 + q4 * 8];
        oacc[n2] = mfma16(pf, vf, oacc[n2]);
      }
    }
  }

  short* ob = outb + wv * 16 * 768;
#pragma unroll
  for (int r = 0; r < 4; ++r) {
    const float inv = 1.f / sm[r];
#pragma unroll
    for (int n2 = 0; n2 < 4; ++n2)
      ob[(q4 * 4 + r) * 768 + n2 * 16 + l15] = f2bf(oacc[n2][r] * inv);
  }
}

// ------- Proj GEMM: out[r][j] = sum_k Xa[r][k]*Pw[j][k] + pb[j] (fp32 out) -----
// A rows gathered from {mt, s} concat; W: bf16 [768][768].
__global__ __launch_bounds__(256) void gemm_proj_k(
    const short* __restrict__ mt, const short* __restrict__ sA,
    const short* __restrict__ sh,
    const short* __restrict__ W, const float* __restrict__ bias,
    float* __restrict__ out, int cb0) {
  __shared__ __align__(16) short As[128 * 32];
  __shared__ __align__(16) short Bs[128 * 32];
  const int tid = threadIdx.x;
  const int lane = tid & 63, wv = tid >> 6;
  const int l15 = lane & 15, q4 = lane >> 4;
  const int m0 = blockIdx.x * 128, n0 = blockIdx.y * 128;
  const short* s = blockIdx.z ? sh : sA;
  const int wm = wv & 1, wn = wv >> 1;

  const int s0 = tid, s1 = tid + 256;
  const int r0 = s0 >> 2, c0 = (s0 & 3) * 8;
  const int r1 = s1 >> 2, c1 = (s1 & 3) * 8;
  const int ra = m0 + r0, rb = m0 + r1;
  const int ba_ = ra / 384, na = ra % 384;
  const int bb_ = rb / 384, nb = rb % 384;
  const short* ap0 = ((na < 128) ? (mt + ((long)ba_ * 128 + na) * 768)
                                 : (s + ((long)ba_ * 256 + (na - 128)) * 768)) + c0;
  const short* ap1 = ((nb < 128) ? (mt + ((long)bb_ * 128 + nb) * 768)
                                 : (s + ((long)bb_ * 256 + (nb - 128)) * 768)) + c1;
  const short* bp0 = W + (long)(n0 + r0) * 768 + c0;
  const short* bp1 = W + (long)(n0 + r1) * 768 + c1;
  short* lA0 = &As[(wv * 64) * 8];
  short* lA1 = &As[(wv * 64 + 256) * 8];
  short* lB0 = &Bs[(wv * 64) * 8];
  short* lB1 = &Bs[(wv * 64 + 256) * 8];

  f32x4 acc[4][4] = {};
  for (int k0 = 0; k0 < 768; k0 += 32) {
    __syncthreads();
    gload16(ap0 + k0, lA0);
    gload16(ap1 + k0, lA1);
    gload16(bp0 + k0, lB0);
    gload16(bp1 + k0, lB1);
    __syncthreads();
    short8 af[4], bf[4];
#pragma unroll
    for (int i = 0; i < 4; ++i)
      af[i] = *(const short8*)&As[(wm * 64 + i * 16 + l15) * 32 + q4 * 8];
#pragma unroll
    for (int j = 0; j < 4; ++j)
      bf[j] = *(const short8*)&Bs[(wn * 64 + j * 16 + l15) * 32 + q4 * 8];
#pragma unroll
    for (int i = 0; i < 4; ++i)
#pragma unroll
      for (int j = 0; j < 4; ++j)
        acc[i][j] = mfma16(af[i], bf[j], acc[i][j]);
  }
#pragma unroll
  for (int j = 0; j < 4; ++j) {
    const int col = n0 + wn * 64 + j * 16 + l15;
    const float bvv = bias[col];
#pragma unroll
    for (int i = 0; i < 4; ++i)
#pragma unroll
      for (int r = 0; r < 4; ++r) {
        const int row = m0 + wm * 64 + i * 16 + q4 * 4 + r;
        out[(long)blockIdx.z * 18874368 + ((long)cb0 * 384 + row) * 768 + col] =
            acc[i][j][r] + bvv;
      }
  }
}

extern "C" void kernel_launch(void* const* d_in, const int* in_sizes, int n_in,
                              void* d_out, int out_size, void* d_ws, size_t ws_size,
                              hipStream_t stream) {
  (void)in_sizes; (void)n_in; (void)out_size;
  const float* x  = (const float*)d_in[0];
  const float* xh = (const float*)d_in[1];
  const float* qw = (const float*)d_in[2];
  const float* pw = (const float*)d_in[3];
  const float* pb = (const float*)d_in[4];
  float* out = (float*)d_out;

  // fixed bf16 weights: qkv_w (2304x768) + proj_w (768x768)
  const long qwSz = 2304L * 768 * 2;   // 3,538,944
  const long pwSz = 768L * 768 * 2;    // 1,179,648
  const long fixedW = qwSz + pwSz;
  // per-batch ws bytes (all bf16): 2 x-bf16 + 2 QKV + 3 attention outputs
  const long perBatch = (2L * 384 * 768 + 2L * 384 * 2304 + 640L * 768) * 2;  // 5,701,632
  int CB = 64;
  while (CB > 1 && (long)CB * perBatch + fixedW > (long)ws_size) CB >>= 1;

  char* ws = (char*)d_ws;
  short* qwbf = (short*)ws;
  short* pwbf = (short*)(ws + qwSz);
  char* dyn = ws + fixedW;
  const long xbfSz = (long)CB * 384 * 768 * 2;
  const long qkvSz = (long)CB * 384 * 2304 * 2;
  const long mtSz  = (long)CB * 128 * 768 * 2;
  const long sSz   = (long)CB * 256 * 768 * 2;
  short* xbf  = (short*)dyn;
  short* xhbf = (short*)(dyn + xbfSz);
  short* qkvx = (short*)(dyn + 2 * xbfSz);
  short* qkvh = (short*)(dyn + 2 * xbfSz + qkvSz);
  short* amt  = (short*)(dyn + 2 * xbfSz + 2 * qkvSz);
  short* as_  = (short*)(dyn + 2 * xbfSz + 2 * qkvSz + mtSz);
  short* ash  = (short*)(dyn + 2 * xbfSz + 2 * qkvSz + mtSz + sSz);

  // weights -> bf16 (once)
  cvt_k<<<864, 256, 0, stream>>>(qw, qwbf, 2304L * 768 / 8);
  cvt_k<<<288, 256, 0, stream>>>(pw, pwbf, 768L * 768 / 8);

  const int nch = 64 / CB;
  for (int c = 0; c < nch; ++c) {
    const int cb0 = c * CB;
    const long n8 = (long)CB * 384 * 768 / 8;
    cvt_k<<<2048, 256, 0, stream>>>(x + (long)cb0 * 384 * 768, xbf, n8);
    cvt_k<<<2048, 256, 0, stream>>>(xh + (long)cb0 * 384 * 768, xhbf, n8);
    dim3 g1(CB * 3, 18, 2);
    gemm_qkv_k<<<g1, 256, 0, stream>>>(xbf, xhbf, qwbf, qkvx, qkvh);
    attn_k<128><<<CB * 12 * 2, 256, 0, stream>>>(qkvx, qkvh, amt, as_, ash);
    attn_k<384><<<CB * 12 * 8, 256, 0, stream>>>(qkvx, qkvh, amt, as_, ash);
    dim3 g3(CB * 3, 6, 2);
    gemm_proj_k<<<g3, 256, 0, stream>>>(amt, as_, ash, pwbf, pb, out, cb0);
  }
}

// Round 2
// 755.219 us; speedup vs baseline: 1.4003x; 1.1410x over previous
//
#include <hip/hip_runtime.h>

typedef __attribute__((ext_vector_type(8))) short short8;
typedef __attribute__((ext_vector_type(4))) short bf16x4;
typedef __attribute__((ext_vector_type(4))) float f32x4;

__device__ __forceinline__ f32x4 mfma16(short8 a, short8 b, f32x4 c) {
  return __builtin_amdgcn_mfma_f32_16x16x32_bf16(a, b, c, 0, 0, 0);
}

__device__ __forceinline__ short f2bf(float f) {  // RNE float->bf16
  union { float f; unsigned u; } v; v.f = f;
  unsigned r = (v.u + 0x7fffu + ((v.u >> 16) & 1u)) >> 16;
  return (short)r;
}

// Async global->LDS, 16B per lane. LDS dest must be the wave-uniform base;
// HW writes base + lane*16 (linear). Source address is per-lane.
__device__ __forceinline__ void gload16(const short* g, short* l) {
  __builtin_amdgcn_global_load_lds(
      (const __attribute__((address_space(1))) void*)g,
      (__attribute__((address_space(3))) void*)l, 16, 0, 0);
}

// ---------------- fp32 -> bf16 streaming convert ----------------
__global__ __launch_bounds__(256) void cvt_k(const float* __restrict__ src,
                                             short* __restrict__ dst, long n8) {
  long i = (long)blockIdx.x * 256 + threadIdx.x;
  const long stride = (long)gridDim.x * 256;
  for (; i < n8; i += stride) {
    float4 a = *(const float4*)(src + i * 8);
    float4 b = *(const float4*)(src + i * 8 + 4);
    short8 o = {f2bf(a.x), f2bf(a.y), f2bf(a.z), f2bf(a.w),
                f2bf(b.x), f2bf(b.y), f2bf(b.z), f2bf(b.w)};
    *(short8*)(dst + i * 8) = o;
  }
}

// ---------------- QKV GEMM: O[r][j] = sum_k X[r][k] * W[j][k] ----------------
__global__ __launch_bounds__(256) void gemm_qkv_k(
    const short* __restrict__ A0, const short* __restrict__ A1,
    const short* __restrict__ W,
    short* __restrict__ O0, short* __restrict__ O1) {
  __shared__ __align__(16) short As[128 * 32];
  __shared__ __align__(16) short Bs[128 * 32];
  const int tid = threadIdx.x;
  const int lane = tid & 63, wv = tid >> 6;
  const int l15 = lane & 15, q4 = lane >> 4;
  const int m0 = blockIdx.x * 128, n0 = blockIdx.y * 128;
  const short* A = blockIdx.z ? A1 : A0;
  short* O = blockIdx.z ? O1 : O0;
  const int wm = wv & 1, wn = wv >> 1;

  const int s0 = tid, s1 = tid + 256;
  const long ga0 = (long)(m0 + (s0 >> 2)) * 768 + (s0 & 3) * 8;
  const long ga1 = (long)(m0 + (s1 >> 2)) * 768 + (s1 & 3) * 8;
  const long gb0 = (long)(n0 + (s0 >> 2)) * 768 + (s0 & 3) * 8;
  const long gb1 = (long)(n0 + (s1 >> 2)) * 768 + (s1 & 3) * 8;
  short* lA0 = &As[(wv * 64) * 8];
  short* lA1 = &As[(wv * 64 + 256) * 8];
  short* lB0 = &Bs[(wv * 64) * 8];
  short* lB1 = &Bs[(wv * 64 + 256) * 8];

  f32x4 acc[4][4] = {};
  for (int k0 = 0; k0 < 768; k0 += 32) {
    __syncthreads();
    gload16(A + ga0 + k0, lA0);
    gload16(A + ga1 + k0, lA1);
    gload16(W + gb0 + k0, lB0);
    gload16(W + gb1 + k0, lB1);
    __syncthreads();
    short8 af[4], bf[4];
#pragma unroll
    for (int i = 0; i < 4; ++i)
      af[i] = *(const short8*)&As[(wm * 64 + i * 16 + l15) * 32 + q4 * 8];
#pragma unroll
    for (int j = 0; j < 4; ++j)
      bf[j] = *(const short8*)&Bs[(wn * 64 + j * 16 + l15) * 32 + q4 * 8];
#pragma unroll
    for (int i = 0; i < 4; ++i)
#pragma unroll
      for (int j = 0; j < 4; ++j)
        acc[i][j] = mfma16(af[i], bf[j], acc[i][j]);
  }
#pragma unroll
  for (int i = 0; i < 4; ++i)
#pragma unroll
    for (int j = 0; j < 4; ++j) {
      const int col = n0 + wn * 64 + j * 16 + l15;
#pragma unroll
      for (int r = 0; r < 4; ++r) {
        const int row = m0 + wm * 64 + i * 16 + q4 * 4 + r;
        O[(long)row * 2304 + col] = f2bf(acc[i][j][r]);
      }
    }
}

// ---------------- Attention (ws bf16 in, ws bf16 out) ----------------
// One block = 64 queries of one (b,h,kind); wave = 16 queries.
// Double-buffered 64-key K/V tiles (1 barrier per tile), per-wave P tile,
// XOR-swizzled V^T staging (conflict-free scalar transpose writes).
template <int NK>
__global__ __launch_bounds__(256) void attn_k(
    const short* __restrict__ qkvx, const short* __restrict__ qkvh,
    short* __restrict__ omt, short* __restrict__ os, short* __restrict__ osh) {
  constexpr int NT = NK / 16;
  constexpr int KT = NK / 64;
  constexpr int T = (NK == 128) ? 2 : 8;
  __shared__ __align__(16) short kv[2][64 * 72];    // K / swizzled V^T tiles
  __shared__ __align__(16) short sp[2][4][16 * 72]; // per-wave P tile

  const int tid = threadIdx.x, lane = tid & 63, wv = tid >> 6;
  const int l15 = lane & 15, q4 = lane >> 4;
  const int bx = blockIdx.x;
  const int b = bx / (12 * T);
  const int rr = bx % (12 * T);
  const int h = rr / T, t = rr % T;

  const short* src;
  short* outb;
  int q0;
  if (NK == 128) {
    src = qkvx;
    outb = omt + ((long)b * 128 + t * 64) * 768 + h * 64;
    q0 = t * 64;
  } else {
    const int tt = t & 3;
    const bool hs = t >= 4;
    src = hs ? qkvh : qkvx;
    outb = (hs ? osh : os) + ((long)b * 256 + tt * 64) * 768 + h * 64;
    q0 = 128 + tt * 64;
  }
  const short* qb = src + ((long)(b * 384 + q0 + wv * 16)) * 2304 + h * 64;
  const short* kb = src + (long)b * 384 * 2304 + 768 + h * 64;
  const short* vb = kb + 768;

  // staging slots: thread covers (key0,dg0) and (key1,dg1)
  const int key0 = tid >> 3, dg0 = tid & 7;
  const int key1 = key0 + 32, dg1 = dg0;

  short8 qf0 = *(const short8*)(qb + (long)l15 * 2304 + q4 * 8);
  short8 qf1 = *(const short8*)(qb + (long)l15 * 2304 + 32 + q4 * 8);

  // ---- S = Q K^T (double-buffered K tiles, 1 barrier/tile) ----
  f32x4 sacc[NT] = {};
  short8 ka0 = *(const short8*)(kb + (long)key0 * 2304 + dg0 * 8);
  short8 ka1 = *(const short8*)(kb + (long)key1 * 2304 + dg1 * 8);
#pragma unroll
  for (int kt = 0; kt < KT; ++kt) {
    const int buf = kt & 1;
    *(short8*)&kv[buf][key0 * 72 + dg0 * 8] = ka0;
    *(short8*)&kv[buf][key1 * 72 + dg1 * 8] = ka1;
    __syncthreads();  // drains this wave's lgkm (prev reads) + makes tile visible
    if (kt + 1 < KT) {
      ka0 = *(const short8*)(kb + (long)((kt + 1) * 64 + key0) * 2304 + dg0 * 8);
      ka1 = *(const short8*)(kb + (long)((kt + 1) * 64 + key1) * 2304 + dg1 * 8);
    }
#pragma unroll
    for (int j = 0; j < 4; ++j) {
      short8 kf0 = *(const short8*)&kv[buf][(j * 16 + l15) * 72 + q4 * 8];
      short8 kf1 = *(const short8*)&kv[buf][(j * 16 + l15) * 72 + 32 + q4 * 8];
      sacc[kt * 4 + j] = mfma16(qf0, kf0, sacc[kt * 4 + j]);
      sacc[kt * 4 + j] = mfma16(qf1, kf1, sacc[kt * 4 + j]);
    }
    // no trailing barrier: next iteration writes the other buffer, whose
    // readers drained at this iteration's barrier (syncthreads waits lgkmcnt).
  }

  // prefetch V tile 0 (latency hides under softmax VALU)
  short8 va0 = *(const short8*)(vb + (long)key0 * 2304 + dg0 * 8);
  short8 va1 = *(const short8*)(vb + (long)key1 * 2304 + dg1 * 8);

  // ---- softmax (P packed to bf16 pairs in regs) ----
  const float scale = 0.125f;
  float mx[4] = {-3e38f, -3e38f, -3e38f, -3e38f};
#pragma unroll
  for (int nt = 0; nt < NT; ++nt)
#pragma unroll
    for (int r = 0; r < 4; ++r) mx[r] = fmaxf(mx[r], sacc[nt][r]);
#pragma unroll
  for (int r = 0; r < 4; ++r) {
    mx[r] = fmaxf(mx[r], __shfl_xor(mx[r], 1));
    mx[r] = fmaxf(mx[r], __shfl_xor(mx[r], 2));
    mx[r] = fmaxf(mx[r], __shfl_xor(mx[r], 4));
    mx[r] = fmaxf(mx[r], __shfl_xor(mx[r], 8));
  }
  float sm[4] = {0.f, 0.f, 0.f, 0.f};
  unsigned pb[NT][2];
#pragma unroll
  for (int nt = 0; nt < NT; ++nt) {
    float ev[4];
#pragma unroll
    for (int r = 0; r < 4; ++r) {
      ev[r] = __expf((sacc[nt][r] - mx[r]) * scale);
      sm[r] += ev[r];
    }
    pb[nt][0] = (unsigned)(unsigned short)f2bf(ev[0]) |
                ((unsigned)(unsigned short)f2bf(ev[1]) << 16);
    pb[nt][1] = (unsigned)(unsigned short)f2bf(ev[2]) |
                ((unsigned)(unsigned short)f2bf(ev[3]) << 16);
  }
#pragma unroll
  for (int r = 0; r < 4; ++r) {
    sm[r] += __shfl_xor(sm[r], 1);
    sm[r] += __shfl_xor(sm[r], 2);
    sm[r] += __shfl_xor(sm[r], 4);
    sm[r] += __shfl_xor(sm[r], 8);
  }

  // ---- O = P V (double-buffered swizzled V^T tiles + per-wave P tiles) ----
  f32x4 oacc[4] = {};
#pragma unroll
  for (int kt = 0; kt < KT; ++kt) {
    const int buf = kt & 1;
    char* vt = (char*)&kv[buf][0];
    // V^T transpose store, XOR-swizzled: bank = (key>>1) + 4*(e^dg), conflict-free
#pragma unroll
    for (int e = 0; e < 8; ++e) {
      const int d0 = dg0 * 8 + e;
      *(short*)(vt + ((d0 * 144 + key0 * 2) ^ (dg0 << 4))) = va0[e];
      *(short*)(vt + ((d0 * 144 + key1 * 2) ^ (dg1 << 4))) = va1[e];
    }
    // P tile for this kt (own-wave region; in-wave lgkm ordering suffices)
    short* spw = &sp[buf][wv][0];
#pragma unroll
    for (int nt2 = 0; nt2 < 4; ++nt2) {
#pragma unroll
      for (int p = 0; p < 2; ++p) {
        const unsigned w = pb[kt * 4 + nt2][p];
        spw[(q4 * 4 + 2 * p) * 72 + nt2 * 16 + l15] = (short)(w & 0xffffu);
        spw[(q4 * 4 + 2 * p + 1) * 72 + nt2 * 16 + l15] = (short)(w >> 16);
      }
    }
    __syncthreads();
    if (kt + 1 < KT) {
      va0 = *(const short8*)(vb + (long)((kt + 1) * 64 + key0) * 2304 + dg0 * 8);
      va1 = *(const short8*)(vb + (long)((kt + 1) * 64 + key1) * 2304 + dg1 * 8);
    }
#pragma unroll
    for (int ks = 0; ks < 2; ++ks) {
      short8 pf = *(const short8*)&sp[buf][wv][l15 * 72 + ks * 32 + q4 * 8];
#pragma unroll
      for (int n2 = 0; n2 < 4; ++n2) {
        const int db = n2 * 16 + l15;
        short8 vf = *(const short8*)(vt + ((db * 144 + (ks * 32 + q4 * 8) * 2) ^
                                           (((db >> 3) & 7) << 4)));
        oacc[n2] = mfma16(pf, vf, oacc[n2]);
      }
    }
  }

  short* ob = outb + wv * 16 * 768;
#pragma unroll
  for (int r = 0; r < 4; ++r) {
    const float inv = 1.f / sm[r];
#pragma unroll
    for (int n2 = 0; n2 < 4; ++n2)
      ob[(q4 * 4 + r) * 768 + n2 * 16 + l15] = f2bf(oacc[n2][r] * inv);
  }
}

// ------- Proj GEMM: out[r][j] = sum_k Xa[r][k]*Pw[j][k] + pb[j] (fp32 out) -----
__global__ __launch_bounds__(256) void gemm_proj_k(
    const short* __restrict__ mt, const short* __restrict__ sA,
    const short* __restrict__ sh,
    const short* __restrict__ W, const float* __restrict__ bias,
    float* __restrict__ out, int cb0) {
  __shared__ __align__(16) short As[128 * 32];
  __shared__ __align__(16) short Bs[128 * 32];
  const int tid = threadIdx.x;
  const int lane = tid & 63, wv = tid >> 6;
  const int l15 = lane & 15, q4 = lane >> 4;
  const int m0 = blockIdx.x * 128, n0 = blockIdx.y * 128;
  const short* s = blockIdx.z ? sh : sA;
  const int wm = wv & 1, wn = wv >> 1;

  const int s0 = tid, s1 = tid + 256;
  const int r0 = s0 >> 2, c0 = (s0 & 3) * 8;
  const int r1 = s1 >> 2, c1 = (s1 & 3) * 8;
  const int ra = m0 + r0, rb = m0 + r1;
  const int ba_ = ra / 384, na = ra % 384;
  const int bb_ = rb / 384, nb = rb % 384;
  const short* ap0 = ((na < 128) ? (mt + ((long)ba_ * 128 + na) * 768)
                                 : (s + ((long)ba_ * 256 + (na - 128)) * 768)) + c0;
  const short* ap1 = ((nb < 128) ? (mt + ((long)bb_ * 128 + nb) * 768)
                                 : (s + ((long)bb_ * 256 + (nb - 128)) * 768)) + c1;
  const short* bp0 = W + (long)(n0 + r0) * 768 + c0;
  const short* bp1 = W + (long)(n0 + r1) * 768 + c1;
  short* lA0 = &As[(wv * 64) * 8];
  short* lA1 = &As[(wv * 64 + 256) * 8];
  short* lB0 = &Bs[(wv * 64) * 8];
  short* lB1 = &Bs[(wv * 64 + 256) * 8];

  f32x4 acc[4][4] = {};
  for (int k0 = 0; k0 < 768; k0 += 32) {
    __syncthreads();
    gload16(ap0 + k0, lA0);
    gload16(ap1 + k0, lA1);
    gload16(bp0 + k0, lB0);
    gload16(bp1 + k0, lB1);
    __syncthreads();
    short8 af[4], bf[4];
#pragma unroll
    for (int i = 0; i < 4; ++i)
      af[i] = *(const short8*)&As[(wm * 64 + i * 16 + l15) * 32 + q4 * 8];
#pragma unroll
    for (int j = 0; j < 4; ++j)
      bf[j] = *(const short8*)&Bs[(wn * 64 + j * 16 + l15) * 32 + q4 * 8];
#pragma unroll
    for (int i = 0; i < 4; ++i)
#pragma unroll
      for (int j = 0; j < 4; ++j)
        acc[i][j] = mfma16(af[i], bf[j], acc[i][j]);
  }
#pragma unroll
  for (int j = 0; j < 4; ++j) {
    const int col = n0 + wn * 64 + j * 16 + l15;
    const float bvv = bias[col];
#pragma unroll
    for (int i = 0; i < 4; ++i)
#pragma unroll
      for (int r = 0; r < 4; ++r) {
        const int row = m0 + wm * 64 + i * 16 + q4 * 4 + r;
        out[(long)blockIdx.z * 18874368 + ((long)cb0 * 384 + row) * 768 + col] =
            acc[i][j][r] + bvv;
      }
  }
}

extern "C" void kernel_launch(void* const* d_in, const int* in_sizes, int n_in,
                              void* d_out, int out_size, void* d_ws, size_t ws_size,
                              hipStream_t stream) {
  (void)in_sizes; (void)n_in; (void)out_size;
  const float* x  = (const float*)d_in[0];
  const float* xh = (const float*)d_in[1];
  const float* qw = (const float*)d_in[2];
  const float* pw = (const float*)d_in[3];
  const float* pb = (const float*)d_in[4];
  float* out = (float*)d_out;

  const long qwSz = 2304L * 768 * 2;
  const long pwSz = 768L * 768 * 2;
  const long fixedW = qwSz + pwSz;
  const long perBatch = (2L * 384 * 768 + 2L * 384 * 2304 + 640L * 768) * 2;
  int CB = 64;
  while (CB > 1 && (long)CB * perBatch + fixedW > (long)ws_size) CB >>= 1;

  char* ws = (char*)d_ws;
  short* qwbf = (short*)ws;
  short* pwbf = (short*)(ws + qwSz);
  char* dyn = ws + fixedW;
  const long xbfSz = (long)CB * 384 * 768 * 2;
  const long qkvSz = (long)CB * 384 * 2304 * 2;
  const long mtSz  = (long)CB * 128 * 768 * 2;
  const long sSz   = (long)CB * 256 * 768 * 2;
  short* xbf  = (short*)dyn;
  short* xhbf = (short*)(dyn + xbfSz);
  short* qkvx = (short*)(dyn + 2 * xbfSz);
  short* qkvh = (short*)(dyn + 2 * xbfSz + qkvSz);
  short* amt  = (short*)(dyn + 2 * xbfSz + 2 * qkvSz);
  short* as_  = (short*)(dyn + 2 * xbfSz + 2 * qkvSz + mtSz);
  short* ash  = (short*)(dyn + 2 * xbfSz + 2 * qkvSz + mtSz + sSz);

  cvt_k<<<864, 256, 0, stream>>>(qw, qwbf, 2304L * 768 / 8);
  cvt_k<<<288, 256, 0, stream>>>(pw, pwbf, 768L * 768 / 8);

  const int nch = 64 / CB;
  for (int c = 0; c < nch; ++c) {
    const int cb0 = c * CB;
    const long n8 = (long)CB * 384 * 768 / 8;
    cvt_k<<<2048, 256, 0, stream>>>(x + (long)cb0 * 384 * 768, xbf, n8);
    cvt_k<<<2048, 256, 0, stream>>>(xh + (long)cb0 * 384 * 768, xhbf, n8);
    dim3 g1(CB * 3, 18, 2);
    gemm_qkv_k<<<g1, 256, 0, stream>>>(xbf, xhbf, qwbf, qkvx, qkvh);
    attn_k<128><<<CB * 12 * 2, 256, 0, stream>>>(qkvx, qkvh, amt, as_, ash);
    attn_k<384><<<CB * 12 * 8, 256, 0, stream>>>(qkvx, qkvh, amt, as_, ash);
    dim3 g3(CB * 3, 6, 2);
    gemm_proj_k<<<g3, 256, 0, stream>>>(amt, as_, ash, pwbf, pb, out, cb0);
  }
}

// Round 3
// 712.134 us; speedup vs baseline: 1.4850x; 1.0605x over previous
//
#include <hip/hip_runtime.h>

typedef __attribute__((ext_vector_type(8))) short short8;
typedef __attribute__((ext_vector_type(4))) short bf16x4;
typedef __attribute__((ext_vector_type(4))) float f32x4;

__device__ __forceinline__ f32x4 mfma16(short8 a, short8 b, f32x4 c) {
  return __builtin_amdgcn_mfma_f32_16x16x32_bf16(a, b, c, 0, 0, 0);
}

__device__ __forceinline__ short f2bf(float f) {  // RNE float->bf16
  union { float f; unsigned u; } v; v.f = f;
  unsigned r = (v.u + 0x7fffu + ((v.u >> 16) & 1u)) >> 16;
  return (short)r;
}

// Async global->LDS, 16B per lane. LDS dest must be the wave-uniform base;
// HW writes base + lane*16 (linear). Source address is per-lane.
__device__ __forceinline__ void gload16(const short* g, short* l) {
  __builtin_amdgcn_global_load_lds(
      (const __attribute__((address_space(1))) void*)g,
      (__attribute__((address_space(3))) void*)l, 16, 0, 0);
}

// ---------------- fp32 -> bf16 streaming convert ----------------
__global__ __launch_bounds__(256) void cvt_k(const float* __restrict__ src,
                                             short* __restrict__ dst, long n8) {
  long i = (long)blockIdx.x * 256 + threadIdx.x;
  const long stride = (long)gridDim.x * 256;
  for (; i < n8; i += stride) {
    float4 a = *(const float4*)(src + i * 8);
    float4 b = *(const float4*)(src + i * 8 + 4);
    short8 o = {f2bf(a.x), f2bf(a.y), f2bf(a.z), f2bf(a.w),
                f2bf(b.x), f2bf(b.y), f2bf(b.z), f2bf(b.w)};
    *(short8*)(dst + i * 8) = o;
  }
}

// =============== 256x256 8-phase GEMM core (K=768, BK=64) ===============
// 512 threads = 8 waves (wm = wv&1 row-half, wn = wv>>1 col-quarter).
// LDS 128 KiB: buf b (=ktile&1): A half h at b*65536 + h*16384;
//              B half h at b*65536 + 32768 + h*16384.
// Half layout: [colblk(2)][row(128)][32 bf16], swizzle byte ^= ((byte>>9)&1)<<5
// (st_16x32). global_load_lds writes linearly -> inverse-swizzled SOURCE.
// Stage order: P(t,q0/q1): A-top/A-bot(t+1); P(t,q2/q3): B-top/B-bot(t+2).
// vmcnt(4) once per K-tile (q3, before trailing barrier): at q0 of tile t
// at most the two B(t+1) halves are in flight; all halves of t have landed.
__device__ __forceinline__ void gemm256_core(
    const short* a00, const short* a01, const short* a10, const short* a11,
    const short* b00, const short* b01, const short* b10, const short* b11,
    char* lds, int wv, int lane, f32x4 (&acc)[8][4]) {
  const int l15 = lane & 15, q4 = lane >> 4;
  const int wm = wv & 1, wn = wv >> 1;
  const char* rdA = lds + wm * 16384;
  const char* rdB = lds + 32768 + (wn >> 1) * 16384;
  const int rB0 = (wn & 1) * 64;

  auto stg = [&](int T, int h, int tt) {
    const int t = tt >= 12 ? tt - 12 : tt;  // wrap: harmless, in-bounds
    char* d = lds + (t & 1) * 65536 + T * 32768 + h * 16384 + wv * 2048;
    const short* g0 = T ? (h ? b10 : b00) : (h ? a10 : a00);
    const short* g1 = T ? (h ? b11 : b01) : (h ? a11 : a01);
    gload16(g0 + t * 64, (short*)d);
    gload16(g1 + t * 64, (short*)(d + 1024));
  };
  auto rdfrag = [&](const char* base, int rowl, int ks) -> short8 {
    int off = ks * 8192 + rowl * 64 + q4 * 16;
    off ^= ((off >> 9) & 1) << 5;
    return *(const short8*)(base + off);
  };

  // prologue: K0 fully + B halves of K1; wait K0 landed (<=2 halves out)
  stg(0, 0, 0); stg(0, 1, 0); stg(1, 0, 0); stg(1, 1, 0);
  stg(1, 0, 1); stg(1, 1, 1);
  asm volatile("s_waitcnt vmcnt(4)" ::: "memory");
  __builtin_amdgcn_s_barrier();

  auto ktile = [&](int buf, int t) {
    const char* A = rdA + buf * 65536;
    const char* B = rdB + buf * 65536;
    short8 af[4][2], bfr[4][2];
    // ---- q0: A m0-3 + B n0-1 reads; stage A-top(t+1) ----
#pragma unroll
    for (int m = 0; m < 4; ++m) {
      af[m][0] = rdfrag(A, m * 16 + l15, 0);
      af[m][1] = rdfrag(A, m * 16 + l15, 1);
    }
#pragma unroll
    for (int n = 0; n < 2; ++n) {
      bfr[n][0] = rdfrag(B, rB0 + n * 16 + l15, 0);
      bfr[n][1] = rdfrag(B, rB0 + n * 16 + l15, 1);
    }
    stg(0, 0, t + 1);
    __builtin_amdgcn_s_barrier();
    __builtin_amdgcn_s_setprio(1);
#pragma unroll
    for (int m = 0; m < 4; ++m)
#pragma unroll
      for (int n = 0; n < 2; ++n) {
        acc[m][n] = mfma16(af[m][0], bfr[n][0], acc[m][n]);
        acc[m][n] = mfma16(af[m][1], bfr[n][1], acc[m][n]);
      }
    __builtin_amdgcn_s_setprio(0);
    __builtin_amdgcn_s_barrier();
    // ---- q1: B n2-3 reads; stage A-bot(t+1) ----
#pragma unroll
    for (int n = 2; n < 4; ++n) {
      bfr[n][0] = rdfrag(B, rB0 + n * 16 + l15, 0);
      bfr[n][1] = rdfrag(B, rB0 + n * 16 + l15, 1);
    }
    stg(0, 1, t + 1);
    __builtin_amdgcn_s_barrier();
    __builtin_amdgcn_s_setprio(1);
#pragma unroll
    for (int m = 0; m < 4; ++m)
#pragma unroll
      for (int n = 2; n < 4; ++n) {
        acc[m][n] = mfma16(af[m][0], bfr[n][0], acc[m][n]);
        acc[m][n] = mfma16(af[m][1], bfr[n][1], acc[m][n]);
      }
    __builtin_amdgcn_s_setprio(0);
    __builtin_amdgcn_s_barrier();
    // ---- q2: A m4-7 reads; stage B-top(t+2) ----
#pragma unroll
    for (int m = 0; m < 4; ++m) {
      af[m][0] = rdfrag(A, (m + 4) * 16 + l15, 0);
      af[m][1] = rdfrag(A, (m + 4) * 16 + l15, 1);
    }
    stg(1, 0, t + 2);
    __builtin_amdgcn_s_barrier();
    __builtin_amdgcn_s_setprio(1);
#pragma unroll
    for (int m = 0; m < 4; ++m)
#pragma unroll
      for (int n = 0; n < 2; ++n) {
        acc[m + 4][n] = mfma16(af[m][0], bfr[n][0], acc[m + 4][n]);
        acc[m + 4][n] = mfma16(af[m][1], bfr[n][1], acc[m + 4][n]);
      }
    __builtin_amdgcn_s_setprio(0);
    __builtin_amdgcn_s_barrier();
    // ---- q3: no reads; stage B-bot(t+2); counted vmcnt ----
    stg(1, 1, t + 2);
    __builtin_amdgcn_s_barrier();
    __builtin_amdgcn_s_setprio(1);
#pragma unroll
    for (int m = 0; m < 4; ++m)
#pragma unroll
      for (int n = 2; n < 4; ++n) {
        acc[m + 4][n] = mfma16(af[m][0], bfr[n][0], acc[m + 4][n]);
        acc[m + 4][n] = mfma16(af[m][1], bfr[n][1], acc[m + 4][n]);
      }
    __builtin_amdgcn_s_setprio(0);
    asm volatile("s_waitcnt vmcnt(4)" ::: "memory");
    __builtin_amdgcn_s_barrier();
  };

  for (int g = 0; g < 6; ++g) {
    ktile(0, 2 * g);
    ktile(1, 2 * g + 1);
  }
}

// per-thread staging geometry: slot s = wv*128 + j*64 + lane covers LDS
// phys bytes [s*16, s*16+16); unswizzled u = s*16 ^ (((s>>5)&1)<<5):
// colblk = s>>9, row = (s>>2)&127, colbyte = ((s&3)<<4) ^ (((s>>5)&1)<<5).
__device__ __forceinline__ void stage_geom(int wv, int lane, int* srow, int* coff) {
#pragma unroll
  for (int j = 0; j < 2; ++j) {
    const int s = wv * 128 + j * 64 + lane;
    srow[j] = (s >> 2) & 127;
    coff[j] = (s >> 9) * 32 + (((((s & 3) << 4) ^ (((s >> 5) & 1) << 5))) >> 1);
  }
}

// ---------------- QKV GEMM: O[r][j] = sum_k X[r][k] * W[j][k] ----------------
__global__ __launch_bounds__(512, 2) void gemm_qkv_k(
    const short* __restrict__ A0, const short* __restrict__ A1,
    const short* __restrict__ W,
    short* __restrict__ O0, short* __restrict__ O1) {
  extern __shared__ char lds[];
  const int tid = threadIdx.x, lane = tid & 63, wv = tid >> 6;
  const int l15 = lane & 15, q4 = lane >> 4;
  const int m0 = blockIdx.x * 256, n0 = blockIdx.y * 256;
  const short* A = blockIdx.z ? A1 : A0;
  short* O = blockIdx.z ? O1 : O0;

  int srow[2], coff[2];
  stage_geom(wv, lane, srow, coff);
  const short* a00 = A + (long)(m0 + srow[0]) * 768 + coff[0];
  const short* a01 = A + (long)(m0 + srow[1]) * 768 + coff[1];
  const short* a10 = A + (long)(m0 + 128 + srow[0]) * 768 + coff[0];
  const short* a11 = A + (long)(m0 + 128 + srow[1]) * 768 + coff[1];
  const short* b00 = W + (long)(n0 + srow[0]) * 768 + coff[0];
  const short* b01 = W + (long)(n0 + srow[1]) * 768 + coff[1];
  const short* b10 = W + (long)(n0 + 128 + srow[0]) * 768 + coff[0];
  const short* b11 = W + (long)(n0 + 128 + srow[1]) * 768 + coff[1];

  f32x4 acc[8][4] = {};
  gemm256_core(a00, a01, a10, a11, b00, b01, b10, b11, lds, wv, lane, acc);

  const int wm = wv & 1, wn = wv >> 1;
#pragma unroll
  for (int m = 0; m < 8; ++m)
#pragma unroll
    for (int n = 0; n < 4; ++n) {
      const int col = n0 + wn * 64 + n * 16 + l15;
#pragma unroll
      for (int r = 0; r < 4; ++r) {
        const int row = m0 + wm * 128 + m * 16 + q4 * 4 + r;
        O[(long)row * 2304 + col] = f2bf(acc[m][n][r]);
      }
    }
}

// ---------------- Attention (ws bf16 in, ws bf16 out) ----------------
// One block = 64 queries of one (b,h,kind); wave = 16 queries.
// Double-buffered 64-key K/V tiles (1 barrier per tile), per-wave P tile,
// XOR-swizzled V^T staging (conflict-free scalar transpose writes).
template <int NK>
__global__ __launch_bounds__(256) void attn_k(
    const short* __restrict__ qkvx, const short* __restrict__ qkvh,
    short* __restrict__ omt, short* __restrict__ os, short* __restrict__ osh) {
  constexpr int NT = NK / 16;
  constexpr int KT = NK / 64;
  constexpr int T = (NK == 128) ? 2 : 8;
  __shared__ __align__(16) short kv[2][64 * 72];    // K / swizzled V^T tiles
  __shared__ __align__(16) short sp[2][4][16 * 72]; // per-wave P tile

  const int tid = threadIdx.x, lane = tid & 63, wv = tid >> 6;
  const int l15 = lane & 15, q4 = lane >> 4;
  const int bx = blockIdx.x;
  const int b = bx / (12 * T);
  const int rr = bx % (12 * T);
  const int h = rr / T, t = rr % T;

  const short* src;
  short* outb;
  int q0;
  if (NK == 128) {
    src = qkvx;
    outb = omt + ((long)b * 128 + t * 64) * 768 + h * 64;
    q0 = t * 64;
  } else {
    const int tt = t & 3;
    const bool hs = t >= 4;
    src = hs ? qkvh : qkvx;
    outb = (hs ? osh : os) + ((long)b * 256 + tt * 64) * 768 + h * 64;
    q0 = 128 + tt * 64;
  }
  const short* qb = src + ((long)(b * 384 + q0 + wv * 16)) * 2304 + h * 64;
  const short* kb = src + (long)b * 384 * 2304 + 768 + h * 64;
  const short* vb = kb + 768;

  // staging slots: thread covers (key0,dg0) and (key1,dg1)
  const int key0 = tid >> 3, dg0 = tid & 7;
  const int key1 = key0 + 32, dg1 = dg0;

  short8 qf0 = *(const short8*)(qb + (long)l15 * 2304 + q4 * 8);
  short8 qf1 = *(const short8*)(qb + (long)l15 * 2304 + 32 + q4 * 8);

  // ---- S = Q K^T (double-buffered K tiles, 1 barrier/tile) ----
  f32x4 sacc[NT] = {};
  short8 ka0 = *(const short8*)(kb + (long)key0 * 2304 + dg0 * 8);
  short8 ka1 = *(const short8*)(kb + (long)key1 * 2304 + dg1 * 8);
#pragma unroll
  for (int kt = 0; kt < KT; ++kt) {
    const int buf = kt & 1;
    *(short8*)&kv[buf][key0 * 72 + dg0 * 8] = ka0;
    *(short8*)&kv[buf][key1 * 72 + dg1 * 8] = ka1;
    __syncthreads();  // drains this wave's lgkm (prev reads) + makes tile visible
    if (kt + 1 < KT) {
      ka0 = *(const short8*)(kb + (long)((kt + 1) * 64 + key0) * 2304 + dg0 * 8);
      ka1 = *(const short8*)(kb + (long)((kt + 1) * 64 + key1) * 2304 + dg1 * 8);
    }
#pragma unroll
    for (int j = 0; j < 4; ++j) {
      short8 kf0 = *(const short8*)&kv[buf][(j * 16 + l15) * 72 + q4 * 8];
      short8 kf1 = *(const short8*)&kv[buf][(j * 16 + l15) * 72 + 32 + q4 * 8];
      sacc[kt * 4 + j] = mfma16(qf0, kf0, sacc[kt * 4 + j]);
      sacc[kt * 4 + j] = mfma16(qf1, kf1, sacc[kt * 4 + j]);
    }
    // no trailing barrier: next iteration writes the other buffer, whose
    // readers drained at this iteration's barrier (syncthreads waits lgkmcnt).
  }

  // prefetch V tile 0 (latency hides under softmax VALU)
  short8 va0 = *(const short8*)(vb + (long)key0 * 2304 + dg0 * 8);
  short8 va1 = *(const short8*)(vb + (long)key1 * 2304 + dg1 * 8);

  // ---- softmax (P packed to bf16 pairs in regs) ----
  const float scale = 0.125f;
  float mx[4] = {-3e38f, -3e38f, -3e38f, -3e38f};
#pragma unroll
  for (int nt = 0; nt < NT; ++nt)
#pragma unroll
    for (int r = 0; r < 4; ++r) mx[r] = fmaxf(mx[r], sacc[nt][r]);
#pragma unroll
  for (int r = 0; r < 4; ++r) {
    mx[r] = fmaxf(mx[r], __shfl_xor(mx[r], 1));
    mx[r] = fmaxf(mx[r], __shfl_xor(mx[r], 2));
    mx[r] = fmaxf(mx[r], __shfl_xor(mx[r], 4));
    mx[r] = fmaxf(mx[r], __shfl_xor(mx[r], 8));
  }
  float sm[4] = {0.f, 0.f, 0.f, 0.f};
  unsigned pb[NT][2];
#pragma unroll
  for (int nt = 0; nt < NT; ++nt) {
    float ev[4];
#pragma unroll
    for (int r = 0; r < 4; ++r) {
      ev[r] = __expf((sacc[nt][r] - mx[r]) * scale);
      sm[r] += ev[r];
    }
    pb[nt][0] = (unsigned)(unsigned short)f2bf(ev[0]) |
                ((unsigned)(unsigned short)f2bf(ev[1]) << 16);
    pb[nt][1] = (unsigned)(unsigned short)f2bf(ev[2]) |
                ((unsigned)(unsigned short)f2bf(ev[3]) << 16);
  }
#pragma unroll
  for (int r = 0; r < 4; ++r) {
    sm[r] += __shfl_xor(sm[r], 1);
    sm[r] += __shfl_xor(sm[r], 2);
    sm[r] += __shfl_xor(sm[r], 4);
    sm[r] += __shfl_xor(sm[r], 8);
  }

  // ---- O = P V (double-buffered swizzled V^T tiles + per-wave P tiles) ----
  f32x4 oacc[4] = {};
#pragma unroll
  for (int kt = 0; kt < KT; ++kt) {
    const int buf = kt & 1;
    char* vt = (char*)&kv[buf][0];
    // V^T transpose store, XOR-swizzled: bank = (key>>1) + 4*(e^dg), conflict-free
#pragma unroll
    for (int e = 0; e < 8; ++e) {
      const int d0 = dg0 * 8 + e;
      *(short*)(vt + ((d0 * 144 + key0 * 2) ^ (dg0 << 4))) = va0[e];
      *(short*)(vt + ((d0 * 144 + key1 * 2) ^ (dg1 << 4))) = va1[e];
    }
    // P tile for this kt (own-wave region; in-wave lgkm ordering suffices)
    short* spw = &sp[buf][wv][0];
#pragma unroll
    for (int nt2 = 0; nt2 < 4; ++nt2) {
#pragma unroll
      for (int p = 0; p < 2; ++p) {
        const unsigned w = pb[kt * 4 + nt2][p];
        spw[(q4 * 4 + 2 * p) * 72 + nt2 * 16 + l15] = (short)(w & 0xffffu);
        spw[(q4 * 4 + 2 * p + 1) * 72 + nt2 * 16 + l15] = (short)(w >> 16);
      }
    }
    __syncthreads();
    if (kt + 1 < KT) {
      va0 = *(const short8*)(vb + (long)((kt + 1) * 64 + key0) * 2304 + dg0 * 8);
      va1 = *(const short8*)(vb + (long)((kt + 1) * 64 + key1) * 2304 + dg1 * 8);
    }
#pragma unroll
    for (int ks = 0; ks < 2; ++ks) {
      short8 pf = *(const short8*)&sp[buf][wv][l15 * 72 + ks * 32 + q4 * 8];
#pragma unroll
      for (int n2 = 0; n2 < 4; ++n2) {
        const int db = n2 * 16 + l15;
        short8 vf = *(const short8*)(vt + ((db * 144 + (ks * 32 + q4 * 8) * 2) ^
                                           (((db >> 3) & 7) << 4)));
        oacc[n2] = mfma16(pf, vf, oacc[n2]);
      }
    }
  }

  short* ob = outb + wv * 16 * 768;
#pragma unroll
  for (int r = 0; r < 4; ++r) {
    const float inv = 1.f / sm[r];
#pragma unroll
    for (int n2 = 0; n2 < 4; ++n2)
      ob[(q4 * 4 + r) * 768 + n2 * 16 + l15] = f2bf(oacc[n2][r] * inv);
  }
}

// ------- Proj GEMM: out[r][j] = sum_k Xa[r][k]*Pw[j][k] + pb[j] (fp32 out) -----
__global__ __launch_bounds__(512, 2) void gemm_proj_k(
    const short* __restrict__ mt, const short* __restrict__ sA,
    const short* __restrict__ sh,
    const short* __restrict__ W, const float* __restrict__ bias,
    float* __restrict__ out, int cb0) {
  extern __shared__ char lds[];
  const int tid = threadIdx.x, lane = tid & 63, wv = tid >> 6;
  const int l15 = lane & 15, q4 = lane >> 4;
  const int m0 = blockIdx.x * 256, n0 = blockIdx.y * 256;
  const short* s = blockIdx.z ? sh : sA;

  int srow[2], coff[2];
  stage_geom(wv, lane, srow, coff);
  auto arow = [&](int r) -> const short* {
    const int ba = r / 384, na = r % 384;
    return na < 128 ? (mt + ((long)ba * 128 + na) * 768)
                    : (s + ((long)ba * 256 + (na - 128)) * 768);
  };
  const short* a00 = arow(m0 + srow[0]) + coff[0];
  const short* a01 = arow(m0 + srow[1]) + coff[1];
  const short* a10 = arow(m0 + 128 + srow[0]) + coff[0];
  const short* a11 = arow(m0 + 128 + srow[1]) + coff[1];
  const short* b00 = W + (long)(n0 + srow[0]) * 768 + coff[0];
  const short* b01 = W + (long)(n0 + srow[1]) * 768 + coff[1];
  const short* b10 = W + (long)(n0 + 128 + srow[0]) * 768 + coff[0];
  const short* b11 = W + (long)(n0 + 128 + srow[1]) * 768 + coff[1];

  f32x4 acc[8][4] = {};
  gemm256_core(a00, a01, a10, a11, b00, b01, b10, b11, lds, wv, lane, acc);

  const int wm = wv & 1, wn = wv >> 1;
#pragma unroll
  for (int n = 0; n < 4; ++n) {
    const int col = n0 + wn * 64 + n * 16 + l15;
    const float bvv = bias[col];
#pragma unroll
    for (int m = 0; m < 8; ++m)
#pragma unroll
      for (int r = 0; r < 4; ++r) {
        const int row = m0 + wm * 128 + m * 16 + q4 * 4 + r;
        out[(long)blockIdx.z * 18874368 + ((long)cb0 * 384 + row) * 768 + col] =
            acc[m][n][r] + bvv;
      }
  }
}

extern "C" void kernel_launch(void* const* d_in, const int* in_sizes, int n_in,
                              void* d_out, int out_size, void* d_ws, size_t ws_size,
                              hipStream_t stream) {
  (void)in_sizes; (void)n_in; (void)out_size;
  const float* x  = (const float*)d_in[0];
  const float* xh = (const float*)d_in[1];
  const float* qw = (const float*)d_in[2];
  const float* pw = (const float*)d_in[3];
  const float* pb = (const float*)d_in[4];
  float* out = (float*)d_out;

  const long qwSz = 2304L * 768 * 2;
  const long pwSz = 768L * 768 * 2;
  const long fixedW = qwSz + pwSz;
  const long perBatch = (2L * 384 * 768 + 2L * 384 * 2304 + 640L * 768) * 2;
  int CB = 64;
  while (CB > 2 && (long)CB * perBatch + fixedW > (long)ws_size) CB >>= 1;

  char* ws = (char*)d_ws;
  short* qwbf = (short*)ws;
  short* pwbf = (short*)(ws + qwSz);
  char* dyn = ws + fixedW;
  const long xbfSz = (long)CB * 384 * 768 * 2;
  const long qkvSz = (long)CB * 384 * 2304 * 2;
  const long mtSz  = (long)CB * 128 * 768 * 2;
  const long sSz   = (long)CB * 256 * 768 * 2;
  short* xbf  = (short*)dyn;
  short* xhbf = (short*)(dyn + xbfSz);
  short* qkvx = (short*)(dyn + 2 * xbfSz);
  short* qkvh = (short*)(dyn + 2 * xbfSz + qkvSz);
  short* amt  = (short*)(dyn + 2 * xbfSz + 2 * qkvSz);
  short* as_  = (short*)(dyn + 2 * xbfSz + 2 * qkvSz + mtSz);
  short* ash  = (short*)(dyn + 2 * xbfSz + 2 * qkvSz + mtSz + sSz);

  cvt_k<<<864, 256, 0, stream>>>(qw, qwbf, 2304L * 768 / 8);
  cvt_k<<<288, 256, 0, stream>>>(pw, pwbf, 768L * 768 / 8);

  const int nch = 64 / CB;
  for (int c = 0; c < nch; ++c) {
    const int cb0 = c * CB;
    const long n8 = (long)CB * 384 * 768 / 8;
    cvt_k<<<2048, 256, 0, stream>>>(x + (long)cb0 * 384 * 768, xbf, n8);
    cvt_k<<<2048, 256, 0, stream>>>(xh + (long)cb0 * 384 * 768, xhbf, n8);
    dim3 g1((CB * 384) / 256, 9, 2);
    gemm_qkv_k<<<g1, 512, 131072, stream>>>(xbf, xhbf, qwbf, qkvx, qkvh);
    attn_k<128><<<CB * 12 * 2, 256, 0, stream>>>(qkvx, qkvh, amt, as_, ash);
    attn_k<384><<<CB * 12 * 8, 256, 0, stream>>>(qkvx, qkvh, amt, as_, ash);
    dim3 g3((CB * 384) / 256, 3, 2);
    gemm_proj_k<<<g3, 512, 131072, stream>>>(amt, as_, ash, pwbf, pb, out, cb0);
  }
}